// Round 1
// baseline (187.742 us; speedup 1.0000x reference)
//
#include <hip/hip_runtime.h>
#include <hip/hip_bf16.h>
#include <math.h>

typedef __bf16 bf16_8 __attribute__((ext_vector_type(8)));
typedef float f32x4 __attribute__((ext_vector_type(4)));

#define D_ 256
#define S_ 128
#define E_ 512
#define MPE_ 4096
#define B_ 2
#define N_ 4096
#define M_TOT (B_*N_)   // 8192

__device__ __forceinline__ ushort f2b(float f) {
  union { float f; uint u; } x; x.f = f;
  uint r = (x.u + 0x7FFFu + ((x.u >> 16) & 1u)) >> 16;
  return (ushort)r;
}
__device__ __forceinline__ float b2f(ushort b) {
  union { uint u; float f; } x; x.u = ((uint)b) << 16;
  return x.f;
}

// ---------------- LayerNorm: one wave per row ----------------
__global__ __launch_bounds__(256) void ln_kernel(const float* __restrict__ q,
    const float* __restrict__ w, const float* __restrict__ b,
    ushort* __restrict__ x) {
  int wid = threadIdx.x >> 6, lane = threadIdx.x & 63;
  int row = blockIdx.x * 4 + wid;
  const float* qr = q + (size_t)row * D_;
  float4 v = *(const float4*)(qr + lane * 4);
  float s  = v.x + v.y + v.z + v.w;
  float ss = v.x*v.x + v.y*v.y + v.z*v.z + v.w*v.w;
  #pragma unroll
  for (int off = 32; off; off >>= 1) {
    s  += __shfl_xor(s, off);
    ss += __shfl_xor(ss, off);
  }
  float mu   = s * (1.0f / 256.0f);
  float var  = ss * (1.0f / 256.0f) - mu * mu;
  float rstd = rsqrtf(var + 1e-5f);
  ushort4 o;
  float vv[4] = {v.x, v.y, v.z, v.w};
  ushort ot[4];
  #pragma unroll
  for (int j = 0; j < 4; ++j) {
    int c = lane * 4 + j;
    ot[j] = f2b((vv[j] - mu) * rstd * w[c] + b[c]);
  }
  o.x = ot[0]; o.y = ot[1]; o.z = ot[2]; o.w = ot[3];
  *(ushort4*)(x + (size_t)row * D_ + lane * 4) = o;
}

// ---------------- weight transpose + cast: in f32 [R][C] -> out bf16 [C][R] ----------------
__global__ void wt_kernel(const float* __restrict__ in, ushort* __restrict__ out,
                          int R, int C) {
  int o = blockIdx.x * 256 + threadIdx.x;
  if (o >= R * C) return;
  int c = o / R, r = o - c * R;
  out[o] = f2b(in[r * C + c]);
}

// ---------------- GEMM: A[M][K] bf16, Bt[N][K] bf16 -> out, tile 128x64, BK=64 ----------------
// EPI 0: silu -> bf16 row-major [M][N]
// EPI 1: + bias -> f32 row-major [M][N]
// EPI 2: silu -> bf16 transposed [N][M_TOT]   (for V^T)
template<int EPI>
__global__ __launch_bounds__(256) void gemm_kernel(
    const ushort* __restrict__ A, const ushort* __restrict__ Bt,
    const float* __restrict__ bias, void* __restrict__ out,
    int M, int N, int K) {
  __shared__ alignas(16) ushort As[128 * 64];
  __shared__ alignas(16) ushort Bs[64 * 64];
  int tid = threadIdx.x;
  int lane = tid & 63, wid = tid >> 6;
  int m0 = blockIdx.x * 128, n0 = blockIdx.y * 64;
  int r16 = lane & 15, kq = lane >> 4;
  f32x4 acc[2][4] = {};
  for (int k0 = 0; k0 < K; k0 += 64) {
    __syncthreads();
    #pragma unroll
    for (int t = 0; t < 4; ++t) {          // A tile: 128x64 = 1024 16B-chunks
      int cid = tid + t * 256;
      int row = cid >> 3, c = cid & 7;
      uint4 d = *(const uint4*)(A + ((size_t)(m0 + row) * K + k0 + c * 8));
      *(uint4*)&As[row * 64 + ((c ^ (row & 7)) * 8)] = d;
    }
    #pragma unroll
    for (int t = 0; t < 2; ++t) {          // B tile: 64x64 = 512 chunks
      int cid = tid + t * 256;
      int row = cid >> 3, c = cid & 7;
      uint4 d = *(const uint4*)(Bt + ((size_t)(n0 + row) * K + k0 + c * 8));
      *(uint4*)&Bs[row * 64 + ((c ^ (row & 7)) * 8)] = d;
    }
    __syncthreads();
    #pragma unroll
    for (int ks = 0; ks < 2; ++ks) {
      bf16_8 af[2], bfr[4];
      int c = ks * 4 + kq;
      #pragma unroll
      for (int fm = 0; fm < 2; ++fm) {
        int r = wid * 32 + fm * 16 + r16;
        af[fm] = *(const bf16_8*)&As[r * 64 + ((c ^ (r & 7)) * 8)];
      }
      #pragma unroll
      for (int fn = 0; fn < 4; ++fn) {
        int r = fn * 16 + r16;
        bfr[fn] = *(const bf16_8*)&Bs[r * 64 + ((c ^ (r & 7)) * 8)];
      }
      #pragma unroll
      for (int fm = 0; fm < 2; ++fm)
        #pragma unroll
        for (int fn = 0; fn < 4; ++fn)
          acc[fm][fn] = __builtin_amdgcn_mfma_f32_16x16x32_bf16(af[fm], bfr[fn], acc[fm][fn], 0, 0, 0);
    }
  }
  #pragma unroll
  for (int fm = 0; fm < 2; ++fm)
    #pragma unroll
    for (int fn = 0; fn < 4; ++fn)
      #pragma unroll
      for (int reg = 0; reg < 4; ++reg) {
        int ml = wid * 32 + fm * 16 + kq * 4 + reg;
        int nl = fn * 16 + r16;
        size_t gm = m0 + ml, gn = n0 + nl;
        float val = acc[fm][fn][reg] + bias[gn];
        if (EPI == 0) {
          float y = val / (1.0f + expf(-val));
          ((ushort*)out)[gm * N + gn] = f2b(y);
        } else if (EPI == 2) {
          float y = val / (1.0f + expf(-val));
          ((ushort*)out)[gn * (size_t)M_TOT + gm] = f2b(y);
        } else {
          ((float*)out)[gm * N + gn] = val;
        }
      }
}

// ---------------- RoPE: base[8192][128] -> Q,K bf16 ----------------
__global__ __launch_bounds__(256) void rope_kernel(const ushort* __restrict__ base,
    const float* __restrict__ qw, const float* __restrict__ qb,
    const float* __restrict__ kw, const float* __restrict__ kb,
    ushort* __restrict__ Q, ushort* __restrict__ Kk) {
  int g = blockIdx.x * 256 + threadIdx.x;  // 8192*64 total
  int row = g >> 6, i = g & 63;
  int n = row & (N_ - 1);
  float invf = powf(10000.0f, -(float)i * (1.0f / 64.0f));
  float sv, cv;
  sincosf((float)n * invf, &sv, &cv);
  float b1 = b2f(base[row * S_ + i]), b2 = b2f(base[row * S_ + 64 + i]);
  float x1q = b1 * qw[i] + qb[i], x2q = b2 * qw[64 + i] + qb[64 + i];
  Q[row * S_ + i]      = f2b(x1q * cv - x2q * sv);
  Q[row * S_ + 64 + i] = f2b(x2q * cv + x1q * sv);
  float x1k = b1 * kw[i] + kb[i], x2k = b2 * kw[64 + i] + kb[64 + i];
  Kk[row * S_ + i]      = f2b(x1k * cv - x2k * sv);
  Kk[row * S_ + 64 + i] = f2b(x2k * cv + x1k * sv);
}

// ---------------- fused attention: kvu = u * (relu(qk/mpe+bias)^2 @ v) ----------------
// grid (64 m-tiles, 4 e-chunks, 2 batches), block 256 (4 waves as 2x2)
__global__ __launch_bounds__(256) void attn_kernel(
    const ushort* __restrict__ Q, const ushort* __restrict__ Kd,
    const ushort* __restrict__ VT, const ushort* __restrict__ U,
    const float* __restrict__ w_rel, ushort* __restrict__ KVU) {
  __shared__ alignas(16) ushort Qs[64 * 128];
  __shared__ alignas(16) ushort Ks[64 * 128];
  __shared__ alignas(16) ushort Ps[64 * 64];
  __shared__ alignas(16) ushort Vs[128 * 64];
  __shared__ float Wr[128];
  int tid = threadIdx.x, lane = tid & 63, wid = tid >> 6;
  int b  = blockIdx.z;
  int m0 = blockIdx.x * 64;
  int e0 = blockIdx.y * 128;
  int r16 = lane & 15, kq = lane >> 4;
  int wm = wid >> 1, wh = wid & 1;
  #pragma unroll
  for (int t = 0; t < 4; ++t) {            // stage Q once: 64x128 = 1024 chunks
    int cid = tid + t * 256;
    int row = cid >> 4, c = cid & 15;
    uint4 d = *(const uint4*)(Q + ((size_t)(b * N_ + m0 + row) * S_ + c * 8));
    *(uint4*)&Qs[row * 128 + ((c ^ (row & 7)) * 8)] = d;
  }
  f32x4 pv[2][4] = {};
  const float inv_mpe = 1.0f / (float)MPE_;
  for (int n0 = 0; n0 < N_; n0 += 64) {
    __syncthreads();
    #pragma unroll
    for (int t = 0; t < 4; ++t) {          // K tile 64x128
      int cid = tid + t * 256;
      int row = cid >> 4, c = cid & 15;
      uint4 d = *(const uint4*)(Kd + ((size_t)(b * N_ + n0 + row) * S_ + c * 8));
      *(uint4*)&Ks[row * 128 + ((c ^ (row & 7)) * 8)] = d;
    }
    #pragma unroll
    for (int t = 0; t < 4; ++t) {          // V^T tile: 128e x 64n
      int cid = tid + t * 256;
      int row = cid >> 3, c = cid & 7;
      uint4 d = *(const uint4*)(VT + ((size_t)(e0 + row) * M_TOT + b * N_ + n0 + c * 8));
      *(uint4*)&Vs[row * 64 + ((c ^ (row & 7)) * 8)] = d;
    }
    if (tid < 127) Wr[tid] = w_rel[4095 + n0 - m0 - 63 + tid];
    __syncthreads();
    // S = Q K^T  (64m x 64n over s=128)
    f32x4 sacc[2][2] = {};
    #pragma unroll
    for (int ks = 0; ks < 4; ++ks) {
      bf16_8 af[2], bfr[2];
      int c = ks * 4 + kq;
      #pragma unroll
      for (int fm = 0; fm < 2; ++fm) {
        int r = wm * 32 + fm * 16 + r16;
        af[fm] = *(const bf16_8*)&Qs[r * 128 + ((c ^ (r & 7)) * 8)];
      }
      #pragma unroll
      for (int fn = 0; fn < 2; ++fn) {
        int r = wh * 32 + fn * 16 + r16;
        bfr[fn] = *(const bf16_8*)&Ks[r * 128 + ((c ^ (r & 7)) * 8)];
      }
      #pragma unroll
      for (int fm = 0; fm < 2; ++fm)
        #pragma unroll
        for (int fn = 0; fn < 2; ++fn)
          sacc[fm][fn] = __builtin_amdgcn_mfma_f32_16x16x32_bf16(af[fm], bfr[fn], sacc[fm][fn], 0, 0, 0);
    }
    // transform S -> P (bf16 in LDS)
    #pragma unroll
    for (int fm = 0; fm < 2; ++fm)
      #pragma unroll
      for (int fn = 0; fn < 2; ++fn)
        #pragma unroll
        for (int reg = 0; reg < 4; ++reg) {
          int ml = wm * 32 + fm * 16 + kq * 4 + reg;
          int nl = wh * 32 + fn * 16 + r16;
          float t = sacc[fm][fn][reg] * inv_mpe + Wr[63 + nl - ml];
          t = fmaxf(t, 0.0f);
          int nc = nl >> 3;
          Ps[ml * 64 + ((nc ^ (ml & 7)) * 8) + (nl & 7)] = f2b(t * t);
        }
    __syncthreads();
    // PV: acc += P[64m x 64n] @ V[64n x 128e]
    #pragma unroll
    for (int ks = 0; ks < 2; ++ks) {
      int c = ks * 4 + kq;
      bf16_8 af[2], bfr[4];
      #pragma unroll
      for (int fm = 0; fm < 2; ++fm) {
        int r = wm * 32 + fm * 16 + r16;
        af[fm] = *(const bf16_8*)&Ps[r * 64 + ((c ^ (r & 7)) * 8)];
      }
      #pragma unroll
      for (int fe = 0; fe < 4; ++fe) {
        int r = wh * 64 + fe * 16 + r16;
        bfr[fe] = *(const bf16_8*)&Vs[r * 64 + ((c ^ (r & 7)) * 8)];
      }
      #pragma unroll
      for (int fm = 0; fm < 2; ++fm)
        #pragma unroll
        for (int fe = 0; fe < 4; ++fe)
          pv[fm][fe] = __builtin_amdgcn_mfma_f32_16x16x32_bf16(af[fm], bfr[fe], pv[fm][fe], 0, 0, 0);
    }
  }
  // epilogue: KVU = bf16(u * pv)
  #pragma unroll
  for (int fm = 0; fm < 2; ++fm)
    #pragma unroll
    for (int fe = 0; fe < 4; ++fe)
      #pragma unroll
      for (int reg = 0; reg < 4; ++reg) {
        int ml = wm * 32 + fm * 16 + kq * 4 + reg;
        int el = wh * 64 + fe * 16 + r16;
        size_t grow = (size_t)b * N_ + m0 + ml;
        size_t ge = e0 + el;
        float uu = b2f(U[grow * E_ + ge]);
        KVU[grow * E_ + ge] = f2b(uu * pv[fm][fe][reg]);
      }
}

extern "C" void kernel_launch(void* const* d_in, const int* in_sizes, int n_in,
                              void* d_out, int out_size, void* d_ws, size_t ws_size,
                              hipStream_t stream) {
  const float* query = (const float*)d_in[0];
  const float* ln_w  = (const float*)d_in[1];
  const float* ln_b  = (const float*)d_in[2];
  const float* Wu    = (const float*)d_in[3];
  const float* bu    = (const float*)d_in[4];
  const float* Wv    = (const float*)d_in[5];
  const float* bv    = (const float*)d_in[6];
  const float* Wbase = (const float*)d_in[7];
  const float* bbase = (const float*)d_in[8];
  const float* q_w   = (const float*)d_in[9];
  const float* q_b   = (const float*)d_in[10];
  const float* k_w   = (const float*)d_in[11];
  const float* k_b   = (const float*)d_in[12];
  const float* w_rel = (const float*)d_in[13];
  const float* Wo    = (const float*)d_in[14];
  const float* bo    = (const float*)d_in[15];
  float* out = (float*)d_out;

  char* ws = (char*)d_ws;
  ushort* X    = (ushort*)(ws);                     // 8192*256  (4 MB)
  ushort* U    = (ushort*)(ws + (4u  << 20));       // 8192*512  (8 MB)
  ushort* VT   = (ushort*)(ws + (12u << 20));       // 512*8192  (8 MB)
  ushort* BASE = (ushort*)(ws + (20u << 20));       // 8192*128  (2 MB)
  ushort* Qb   = (ushort*)(ws + (22u << 20));       // 2 MB
  ushort* Kb   = (ushort*)(ws + (24u << 20));       // 2 MB
  ushort* KVU  = (ushort*)(ws + (26u << 20));       // 8 MB
  ushort* WUT  = (ushort*)(ws + (34u << 20));
  ushort* WVT  = (ushort*)(ws + (34u << 20) + 512*256*2);
  ushort* WBT  = (ushort*)(ws + (34u << 20) + 2*512*256*2);
  ushort* WOT  = (ushort*)(ws + (34u << 20) + 2*512*256*2 + 128*256*2);

  ln_kernel<<<2048, 256, 0, stream>>>(query, ln_w, ln_b, X);
  wt_kernel<<<(512*256 + 255) / 256, 256, 0, stream>>>(Wu, WUT, 256, 512);
  wt_kernel<<<(512*256 + 255) / 256, 256, 0, stream>>>(Wv, WVT, 256, 512);
  wt_kernel<<<(128*256 + 255) / 256, 256, 0, stream>>>(Wbase, WBT, 256, 128);
  wt_kernel<<<(512*256 + 255) / 256, 256, 0, stream>>>(Wo, WOT, 512, 256);
  gemm_kernel<0><<<dim3(64, 8), 256, 0, stream>>>(X, WUT, bu, U, 8192, 512, 256);
  gemm_kernel<2><<<dim3(64, 8), 256, 0, stream>>>(X, WVT, bv, VT, 8192, 512, 256);
  gemm_kernel<0><<<dim3(64, 2), 256, 0, stream>>>(X, WBT, bbase, BASE, 8192, 128, 256);
  rope_kernel<<<2048, 256, 0, stream>>>(BASE, q_w, q_b, k_w, k_b, Qb, Kb);
  attn_kernel<<<dim3(64, 4, 2), 256, 0, stream>>>(Qb, Kb, VT, U, w_rel, KVU);
  gemm_kernel<1><<<dim3(64, 4), 256, 0, stream>>>(KVU, WOT, bo, out, 8192, 256, 512);
}